// Round 9
// baseline (275.668 us; speedup 1.0000x reference)
//
#include <hip/hip_runtime.h>
#include <hip/hip_bf16.h>

typedef unsigned short u16;
typedef unsigned int u32;
typedef __attribute__((ext_vector_type(8))) short s8v;    // 8 bf16 (4 VGPRs) — MFMA A/B frag
typedef __attribute__((ext_vector_type(4))) float f4v;    // MFMA C/D frag
typedef __attribute__((ext_vector_type(4))) unsigned short u16x4;
typedef __attribute__((ext_vector_type(4))) unsigned int u32x4;

#define MFMA16(a,b,c) __builtin_amdgcn_mfma_f32_16x16x32_bf16((a),(b),(c),0,0,0)

#define TOKENS 8192        // 4 * 2048
#define SEQ    2048
#define NH     16
#define DH     64
#define DIMK   1024
// fold 1/sqrt(64) * log2(e) into Q so P = exp2(S) directly
#define QPRE   0.18033688f

#if defined(__has_builtin)
#if __has_builtin(__builtin_amdgcn_exp2f)
#define EXP2(x) __builtin_amdgcn_exp2f(x)
#else
#define EXP2(x) __expf((x) * 0.69314718f)
#endif
#else
#define EXP2(x) __expf((x) * 0.69314718f)
#endif

// ---- bf16 helpers (round-to-nearest-even) ----
__device__ __forceinline__ u16 f2bf(float x){
  union { float f; u32 u; } v; v.f = x;
  u32 r = v.u + 0x7FFFu + ((v.u >> 16) & 1u);
  return (u16)(r >> 16);
}

// async global->LDS, 16B per lane; LDS dest = wave-uniform base + lane*16
__device__ __forceinline__ void gld16(const u16* g, u16* s){
  __builtin_amdgcn_global_load_lds(
      (const __attribute__((address_space(1))) unsigned int*)(const void*)g,
      (__attribute__((address_space(3))) unsigned int*)(void*)s,
      16, 0, 0);
}

// ---- cast fp32 -> bf16 (x) ----
__global__ __launch_bounds__(256) void k_cast(const float* __restrict__ src,
                                              u16* __restrict__ dst){
  int i = (blockIdx.x * 256 + threadIdx.x) * 4;
  float4 v = *(const float4*)(src + i);
  u16x4 vh;
  float a[4] = {v.x, v.y, v.z, v.w};
#pragma unroll
  for (int j = 0; j < 4; j++) vh[j] = f2bf(a[j]);
  *(u16x4*)(dst + i) = vh;
}

// ---- transpose weights to n-major bf16: out[n][k] = src[k][n] ----
__global__ __launch_bounds__(256) void k_transpose(const float* __restrict__ s0, int c0,
                                                   const float* __restrict__ s1, int c1,
                                                   int K, u16* __restrict__ dh){
  __shared__ float tile[64][65];
  int nb = blockIdx.x * 64, kb = blockIdx.y * 64;
  int tr = threadIdx.x >> 6, tc = threadIdx.x & 63;
#pragma unroll
  for (int i = 0; i < 16; i++){
    int k = kb + tr + i * 4, n = nb + tc;
    float v = (n < c0) ? s0[(size_t)k * c0 + n] : s1[(size_t)k * c1 + (n - c0)];
    tile[tr + i * 4][tc] = v;
  }
  __syncthreads();
#pragma unroll
  for (int i = 0; i < 16; i++){
    int nl = tr + i * 4, kl = tc;
    dh[(size_t)(nb + nl) * K + (kb + kl)] = f2bf(tile[kl][nl]);
  }
}

// ===========================================================================
// QKV GEMM — 256x256 tile, BK=64, 512 threads (8 waves, 2M x 4N).
// NEW this round: single-buffered 64 KiB LDS -> 2 blocks/CU (was 128 KiB =
// 1 block/CU, occupancy 15.8%, nothing-busy counters = latency/sync-bound
// lockstep). K-loop is the round-0-verified 2-phase shape; cross-BLOCK
// overlap (m97/m114 regime) replaces the in-block 8-phase pipeline, which
// measured identical to 2-phase anyway (rounds 0/1). Stage/read swizzle,
// LPT V-first order, epilogues kept. V-bounce now runs in two 128-row
// passes (64 KiB budget).
// ===========================================================================
#define GQ_STAGE_A(h,t) do{ \
  gld16(As + (size_t)(h)*131072 + (size_t)(t)*64,      &lds[(h)*8192 + w*512]); \
  gld16(As + (size_t)(h)*131072 + (size_t)(t)*64 + 32, &lds[(h)*8192 + 4096 + w*512]); }while(0)
#define GQ_STAGE_B(h,t) do{ \
  gld16(Bs + (size_t)(h)*131072 + (size_t)(t)*64,      &lds[16384 + (h)*8192 + w*512]); \
  gld16(Bs + (size_t)(h)*131072 + (size_t)(t)*64 + 32, &lds[16384 + (h)*8192 + 4096 + w*512]); }while(0)
#define GQ_RDA(dst,mh) do{ _Pragma("unroll") for (int i_ = 0; i_ < 4; i_++){ \
  dst[i_][0] = *(const s8v*)&lds[aRB + ((mh)*4+i_)*512]; \
  dst[i_][1] = *(const s8v*)&lds[aRB + 4096 + ((mh)*4+i_)*512]; } }while(0)
#define GQ_RDB(dst,nh) do{ _Pragma("unroll") for (int j_ = 0; j_ < 2; j_++){ \
  dst[j_][0] = *(const s8v*)&lds[bRB + ((nh)*2+j_)*512]; \
  dst[j_][1] = *(const s8v*)&lds[bRB + 4096 + ((nh)*2+j_)*512]; } }while(0)
#define GQ_MMA(aS,bS,mh,nh) do{ __builtin_amdgcn_s_setprio(1); \
  _Pragma("unroll") for (int i_ = 0; i_ < 4; i_++) \
  _Pragma("unroll") for (int j_ = 0; j_ < 2; j_++){ \
    acc[(mh)*4+i_][(nh)*2+j_] = MFMA16(aS[i_][0], bS[j_][0], acc[(mh)*4+i_][(nh)*2+j_]); \
    acc[(mh)*4+i_][(nh)*2+j_] = MFMA16(aS[i_][1], bS[j_][1], acc[(mh)*4+i_][(nh)*2+j_]); } \
  __builtin_amdgcn_s_setprio(0); }while(0)

__global__ __launch_bounds__(512, 2) void k_gemm_qkv(
    const u16* __restrict__ A, const u16* __restrict__ B,
    u16* __restrict__ Qh, u16* __restrict__ Kh, u16* __restrict__ Vth)
{
  __shared__ u16 lds[32768];   // 64 KiB: A [2 halves][2 planes][128r][32c] + B same
  const int tid = threadIdx.x;
  const int w = tid >> 6, lane = tid & 63;
  const int lm = lane & 15, quad = lane >> 4;
  const int wm = w >> 2, wn = w & 3;      // 2 x 4 wave grid; per-wave C: 128x64

  // m-partition XCD swizzle + LPT nt order (V-tiles first)
  const int bid = blockIdx.x;
  const int xcd = bid & 7, slot = bid >> 3;        // slot 0..47
  const int ntr = slot >> 2;                       // 0..11 (dispatch order)
  const int mloc = slot & 3;                       // 0..3
  const int nt = (ntr < 4) ? ntr + 8 : ntr - 4;
  const int m0 = (xcd * 4 + mloc) * 256, n0 = nt * 256;

  // stage-side per-lane source offsets (inverse swizzle applied to GLOBAL col)
  const int srow = lane >> 2;
  const int scol = ((lane & 3) ^ (((lane >> 5) & 1) << 1)) * 8;
  const u16* As = A + (size_t)(m0 + w * 16 + srow) * DIMK + scol;
  const u16* Bs = B + (size_t)(n0 + w * 16 + srow) * DIMK + scol;

  // read-side swizzled LDS bases (u16 units); col ^= 16 when lm >= 8
  const int swz = (lm & 8) << 1;
  const int aRB = wm * 8192 + lm * 32 + ((quad * 8) ^ swz);
  const int bRB = 16384 + (wn >> 1) * 8192 + (wn & 1) * 2048 + lm * 32 + ((quad * 8) ^ swz);

  f4v acc[8][4];
#pragma unroll
  for (int i = 0; i < 8; i++)
#pragma unroll
    for (int j = 0; j < 4; j++) acc[i][j] = (f4v){0.f, 0.f, 0.f, 0.f};

  s8v aA[4][2], aB[4][2], bA[2][2], bB[2][2];

  for (int kt = 0; kt < 16; kt++){
    GQ_STAGE_A(0, kt); GQ_STAGE_A(1, kt);
    GQ_STAGE_B(0, kt); GQ_STAGE_B(1, kt);
    __syncthreads();    // compiler drains vmcnt(0) before the barrier
    GQ_RDA(aA, 0); GQ_RDA(aB, 1);
    GQ_RDB(bA, 0); GQ_RDB(bB, 1);
    GQ_MMA(aA, bA, 0, 0); GQ_MMA(aA, bB, 0, 1);
    GQ_MMA(aB, bA, 1, 0); GQ_MMA(aB, bB, 1, 1);
    __syncthreads();    // all reads done before next-kt staging overwrites
  }

  // epilogue: C/D layout col = lane&15, row = quad*4+reg  [m89-verified]
  if (nt < 8){
    // Q / K tiles: direct stores (16 consecutive u16 per quad-row = 32B segs)
#pragma unroll
    for (int ig = 0; ig < 8; ig++)
#pragma unroll
      for (int jg = 0; jg < 4; jg++){
        const int gn = n0 + wn * 64 + jg * 16 + lm;
#pragma unroll
        for (int r = 0; r < 4; r++){
          const int gm = m0 + wm * 128 + ig * 16 + quad * 4 + r;
          float v = acc[ig][jg][r];
          if (gn < 1024){                       // Q, token-major, pre-scaled
            Qh[(size_t)gm * DIMK + gn] = f2bf(v * QPRE);
          } else {                              // K, token-major
            Kh[(size_t)gm * DIMK + (gn - 1024)] = f2bf(v);
          }
        }
      }
  } else {
    // V tile: LDS transpose bounce with tau permutation, TWO 128-row passes
    // (64 KiB budget). Pass p handles dd rows [p*128, p*128+128) — written
    // by waves with (wn>>1)==p (wave-uniform predicate; barriers uniform).
    // Token mapping unchanged from the round-7-verified epilogue:
    //   pos64 = ((ig>>1)&1)*32 + quad*8 + (ig&1)*4 + r,
    //   colb = (wm*2 + (igp>>1))*32 + (igp&1)*16 + quad*4.
    u32* bnc = (u32*)lds;   // [128 rows][128 u32 cols] per pass = 64 KiB
#pragma unroll
    for (int pass = 0; pass < 2; pass++){
      __syncthreads();   // pass 0: drain K-loop; pass 1: all reads of pass 0 done
      if ((wn >> 1) == pass){
#pragma unroll
        for (int igp = 0; igp < 4; igp++)
#pragma unroll
          for (int jg = 0; jg < 4; jg++){
            const int ddl = (wn & 1) * 64 + jg * 16 + lm;    // 0..127 local
            const int colb = (wm * 2 + (igp >> 1)) * 32 + (igp & 1) * 16 + quad * 4;
            u32x4 p;
            p[0] = ((u32)f2bf(acc[2 * igp][jg][1])     << 16) | (u32)f2bf(acc[2 * igp][jg][0]);
            p[1] = ((u32)f2bf(acc[2 * igp][jg][3])     << 16) | (u32)f2bf(acc[2 * igp][jg][2]);
            p[2] = ((u32)f2bf(acc[2 * igp + 1][jg][1]) << 16) | (u32)f2bf(acc[2 * igp + 1][jg][0]);
            p[3] = ((u32)f2bf(acc[2 * igp + 1][jg][3]) << 16) | (u32)f2bf(acc[2 * igp + 1][jg][2]);
            const int col = colb ^ ((lm & 7) << 2);          // involution, 16B-granular
            *(u32x4*)&bnc[ddl * 128 + col] = p;
          }
      }
      __syncthreads();
      // coalesced store: 4 threads per dd-row, 128B each (2x dwordx4 runs of 4)
      const int rowl = tid >> 2, qtr = tid & 3;
      const int df = n0 - 2048 + pass * 128 + rowl;
      const int hh = df >> 6, dd = df & 63;
      const int bbat = m0 >> 11, ii0 = m0 & 2047;
      u32* Vg = (u32*)(Vth + ((size_t)(bbat * NH + hh) * DH + dd) * SEQ + ii0);
#pragma unroll
      for (int c = 0; c < 8; c++){
        const int cc = qtr * 8 + c;
        const int cb = (cc * 4) ^ ((rowl & 7) << 2);
        u32x4 q = *(const u32x4*)&bnc[rowl * 128 + cb];
        *(u32x4*)&Vg[cc * 4] = q;
      }
    }
  }
}

// ---- out-proj GEMM: BM=64 x BN=128, BK=64, m-partition XCD swizzle ----
// Round-7-verified version (round-8 dbuf experiment reverted — total
// regressed ~4 µs with it). 24 KB LDS -> 4 blocks/CU.
__global__ __launch_bounds__(256) void k_gemm_op(
    const u16* __restrict__ A, const u16* __restrict__ B,
    const float* __restrict__ bias, float* __restrict__ Cf)
{
  __shared__ u16 sA[2][64*32], sB[2][128*32];   // 8 + 16 = 24 KB
  const int tid = threadIdx.x, wave = tid >> 6, lane = tid & 63;
  const int lm = lane & 15, quad = lane >> 4;

  const int bid = blockIdx.x;                    // 1024 = 8 xcd x 128 slots
  const int xcd = bid & 7, slot = bid >> 3;      // slot 0..127
  const int nt = slot >> 4, mloc = slot & 15;    // nt 0..7, mloc 0..15
  const int m0 = (xcd * 16 + mloc) * 64, n0 = nt * 128;

  const int cof = (lane & 3) * 8;
  const int rsub = lane >> 2;

  f4v acc[2][4];
#pragma unroll
  for (int i = 0; i < 2; i++)
#pragma unroll
    for (int j = 0; j < 4; j++) acc[i][j] = (f4v){0.f, 0.f, 0.f, 0.f};

  const int wm = (wave >> 1) * 32, wn = (wave & 1) * 64;

  for (int kc = 0; kc < 16; kc++){
    int k = kc * 64;
#pragma unroll
    for (int cc = 0; cc < 2; cc++){
      gld16(A + (size_t)(m0 + wave * 16 + rsub) * DIMK + k + cc * 32 + cof, &sA[cc][wave * 512]);
#pragma unroll
      for (int h = 0; h < 2; h++)
        gld16(B + (size_t)(n0 + h * 64 + wave * 16 + rsub) * DIMK + k + cc * 32 + cof,
              &sB[cc][h * 2048 + wave * 512]);
    }
    __syncthreads();

#pragma unroll
    for (int cc = 0; cc < 2; cc++){
      s8v ah[2], bh[4];
#pragma unroll
      for (int i = 0; i < 2; i++)
        ah[i] = *(const s8v*)&sA[cc][(wm + i * 16 + lm) * 32 + quad * 8];
#pragma unroll
      for (int j = 0; j < 4; j++)
        bh[j] = *(const s8v*)&sB[cc][(wn + j * 16 + lm) * 32 + quad * 8];
#pragma unroll
      for (int i = 0; i < 2; i++)
#pragma unroll
        for (int j = 0; j < 4; j++)
          acc[i][j] = MFMA16(ah[i], bh[j], acc[i][j]);
    }
    __syncthreads();
  }

#pragma unroll
  for (int i = 0; i < 2; i++)
#pragma unroll
    for (int j = 0; j < 4; j++){
      int gn = n0 + wn + j * 16 + lm;
      float bv = bias[gn];
#pragma unroll
      for (int r = 0; r < 4; r++){
        int gm = m0 + wm + i * 16 + quad * 4 + r;
        Cf[(size_t)gm * DIMK + gn] = acc[i][j][r] + bv;
      }
    }
}

// ---- flash attention, max-free softmax, XCD (b,h)-grouping ----
// Swapped QK^T (mfma(K,Q)) puts each lane's P slice lane-local (col=lm=q)
// -> P packs straight into PV A-frags in registers. sP deleted. A-frag
// k-slot j of chunk c holds kv=(2c+(j>>2))*16+quad*4+(j&3), matched by the
// tau ordering of Vth columns (qkv epilogue). dbuf + vmcnt(4) + raw
// barriers. Unchanged (passed rounds 7 and 8).
__global__ __launch_bounds__(256, 2) void k_attn(
    const u16* __restrict__ Qh, const u16* __restrict__ Kh, const u16* __restrict__ Vth,
    u16* __restrict__ Oh)
{
  __shared__ u16 sK[2*4096];       // [buf][c][j(64)][32]   16 KB
  __shared__ u16 sV[2*4096];       // [buf][c][d(64)][32 j-tau] 16 KB

  // XCD-aware (b,h,qt) assignment: 512 blocks = 8 xcd x 8 bh x 8 qt
  const int bid = blockIdx.x;
  const int xcd = bid & 7, slot = bid >> 3;      // slot 0..63
  const int g = xcd * 8 + (slot >> 3);           // (b,h) group 0..63
  const int qt = slot & 7;
  const int b = g >> 4, h = g & 15;

  const int tid = threadIdx.x, wave = tid >> 6, lane = tid & 63;
  const int lm = lane & 15, quad = lane >> 4;
  const int tok0 = b * SEQ + qt * 256;
  const int rsub = lane >> 2;
  // stage-side inverse-swizzled global col16; read-side XOR term (u16)
  const int scof = ((lane & 3) ^ (((lane >> 5) & 1) << 1)) * 8;
  const int rsw = (lm & 8) << 1;

  // Q fragments straight to registers (now the B-operand: n=q=lm)
  s8v qf[2][4];   // [c][ifr]
#pragma unroll
  for (int c = 0; c < 2; c++)
#pragma unroll
    for (int ifr = 0; ifr < 4; ifr++){
      size_t ga = (size_t)(tok0 + wave * 64 + ifr * 16 + lm) * DIMK + h * DH + c * 32 + quad * 8;
      qf[c][ifr] = *(const s8v*)(Qh + ga);
    }

  const f4v fz = (f4v){0.f, 0.f, 0.f, 0.f};   // persistent zero C-operand

  s8v ones;                                   // bf16 1.0 B-fragment for l-sum
#pragma unroll
  for (int j = 0; j < 8; j++) ones[j] = (short)0x3F80;

  f4v oacc[4][4];
  f4v lacc[4];
#pragma unroll
  for (int ifr = 0; ifr < 4; ifr++){
    lacc[ifr] = (f4v){0.f, 0.f, 0.f, 0.f};
#pragma unroll
    for (int fd = 0; fd < 4; fd++) oacc[ifr][fd] = (f4v){0.f, 0.f, 0.f, 0.f};
  }

#define AT_STAGE(p, t) do{ const int jb_ = (t) * 64; \
  _Pragma("unroll") for (int c_ = 0; c_ < 2; c_++){ \
    gld16(Kh + (size_t)(b * SEQ + jb_ + wave * 16 + rsub) * DIMK + h * DH + c_ * 32 + scof, \
          &sK[(p) * 4096 + c_ * 2048 + wave * 512]); \
    gld16(Vth + (size_t)((b * NH + h) * DH + wave * 16 + rsub) * SEQ + jb_ + c_ * 32 + scof, \
          &sV[(p) * 4096 + c_ * 2048 + wave * 512]); } }while(0)
#define AT_BAR() do{ asm volatile("" ::: "memory"); __builtin_amdgcn_s_barrier(); asm volatile("" ::: "memory"); }while(0)

  // prologue: stage kt0 -> buf0
  AT_STAGE(0, 0);

  for (int kt = 0; kt < 32; kt++){
    const int p = kt & 1;
    // prefetch kt+1 into the other buffer (dead re-stage of kt=31 on last)
    AT_STAGE(p ^ 1, (kt < 31) ? (kt + 1) : 31);
    // wait only for kt's 4 loads (kt+1's 4 stay in flight across the barrier)
    asm volatile("s_waitcnt vmcnt(4)" ::: "memory");
    AT_BAR();
    const int pb = p * 4096;

    // K fragments (A-operand now; same reads), reused by all 4 ifr
    s8v kh[2][4];
#pragma unroll
    for (int fn = 0; fn < 4; fn++){
      kh[0][fn] = *(const s8v*)&sK[pb + (fn * 16 + lm) * 32 + ((quad * 8) ^ rsw)];
      kh[1][fn] = *(const s8v*)&sK[pb + 2048 + (fn * 16 + lm) * 32 + ((quad * 8) ^ rsw)];
    }

    // per ifr: swapped S^T = K Q^T (lane: q = ifr*16+lm, kv = fn*16+quad*4+r);
    // P = exp2 in-register; pack to PV A-frags pa[ifr][c]:
    //   element j of chunk c = st[2c+(j>>2)][j&3]  (kv matches tau-ordered V)
    s8v pa[4][2];
#pragma unroll
    for (int ifr = 0; ifr < 4; ifr++){
      f4v st[4];
      __builtin_amdgcn_s_setprio(1);
#pragma unroll
      for (int fn = 0; fn < 4; fn++){
        st[fn] = MFMA16(kh[0][fn], qf[0][ifr], fz);
        st[fn] = MFMA16(kh[1][fn], qf[1][ifr], st[fn]);
      }
      __builtin_amdgcn_s_setprio(0);
#pragma unroll
      for (int fn = 0; fn < 4; fn++)
#pragma unroll
        for (int r = 0; r < 4; r++)
          st[fn][r] = EXP2(st[fn][r]);
#pragma unroll
      for (int c = 0; c < 2; c++){
        union { u32x4 w; s8v v; } u;
#pragma unroll
        for (int w2 = 0; w2 < 4; w2++){
          const int fn = c * 2 + (w2 >> 1);
          const int rr = (w2 & 1) * 2;
          union { float f; u32 u; } a0, a1;
          a0.f = st[fn][rr]; a1.f = st[fn][rr + 1];
          u.w[w2] = __builtin_amdgcn_perm(a1.u, a0.u, 0x07060302);
        }
        pa[ifr][c] = u.v;
      }
    }

    // V fragments (tau-ordered columns; read once, reused by all 4 ifr)
    s8v vreg[2][4];
#pragma unroll
    for (int c = 0; c < 2; c++)
#pragma unroll
      for (int fd = 0; fd < 4; fd++)
        vreg[c][fd] = *(const s8v*)&sV[pb + c * 2048 + (fd * 16 + lm) * 32 + ((quad * 8) ^ rsw)];

    // O += P V ; l += P·1  (all in registers — no LDS round-trip for P)
    __builtin_amdgcn_s_setprio(1);
#pragma unroll
    for (int c = 0; c < 2; c++)
#pragma unroll
      for (int ifr = 0; ifr < 4; ifr++){
#pragma unroll
        for (int fd = 0; fd < 4; fd++)
          oacc[ifr][fd] = MFMA16(pa[ifr][c], vreg[c][fd], oacc[ifr][fd]);
        lacc[ifr] = MFMA16(pa[ifr][c], ones, lacc[ifr]);
      }
    __builtin_amdgcn_s_setprio(0);
    // all waves done reading buf p before iter kt+1 overwrites it
    AT_BAR();
  }

  // normalize + store (lacc[ifr][r] = rowsum for q-row quad*4+r)
#pragma unroll
  for (int ifr = 0; ifr < 4; ifr++){
    float inv[4];
#pragma unroll
    for (int r = 0; r < 4; r++) inv[r] = 1.f / lacc[ifr][r];
#pragma unroll
    for (int fd = 0; fd < 4; fd++){
      int dcol = h * DH + fd * 16 + lm;
#pragma unroll
      for (int r = 0; r < 4; r++){
        int tok = tok0 + wave * 64 + ifr * 16 + quad * 4 + r;
        Oh[(size_t)tok * DIMK + dcol] = f2bf(oacc[ifr][fd][r] * inv[r]);
      }
    }
  }
}

extern "C" void kernel_launch(void* const* d_in, const int* in_sizes, int n_in,
                              void* d_out, int out_size, void* d_ws, size_t ws_size,
                              hipStream_t stream) {
  const float* x   = (const float*)d_in[0];
  const float* Wq  = (const float*)d_in[1];
  const float* Wkv = (const float*)d_in[2];
  const float* Wo  = (const float*)d_in[3];
  const float* bo  = (const float*)d_in[4];
  float* out = (float*)d_out;

  char* ws = (char*)d_ws;
  size_t off = 0;
  auto alloc = [&](size_t bytes) -> u16* {
    u16* p = (u16*)(ws + off);
    off += (bytes + 255) & ~(size_t)255;
    return p;
  };
  const size_t TK2 = (size_t)TOKENS * DIMK * 2;   // 16.78 MB per bf16 plane
  u16* xh  = alloc(TK2);
  u16* Wh  = alloc((size_t)3072 * DIMK * 2);      // [Wq|Wkv]^T  [3072][1024]
  u16* WOh = alloc((size_t)1024 * DIMK * 2);      // Wo^T        [1024][1024]
  u16* Qh  = alloc(TK2);
  u16* Kh  = alloc(TK2);
  u16* Vth = alloc(TK2);
  u16* Oh  = alloc(TK2);

  // 1) cast x to bf16
  k_cast<<<dim3((TOKENS * DIMK) / 1024), 256, 0, stream>>>(x, xh);
  // 2) transpose weights to n-major
  k_transpose<<<dim3(48, 16), 256, 0, stream>>>(Wq, 1024, Wkv, 2048, DIMK, Wh);
  k_transpose<<<dim3(16, 16), 256, 0, stream>>>(Wo, 1024, Wo, 1024, DIMK, WOh);
  // 3) QKV projection: 256x256 2-phase, 64 KiB LDS, 2 blocks/CU, LPT order
  k_gemm_qkv<<<dim3(384), 512, 0, stream>>>(xh, Wh, Qh, Kh, Vth);
  // 4) flash attention: in-register P, 64 q-rows/wave, 2 blocks/CU
  k_attn<<<dim3(512), 256, 0, stream>>>(Qh, Kh, Vth, Oh);
  // 5) output projection + bias: round-7 form (4 blocks/CU)
  k_gemm_op<<<dim3(1024), 256, 0, stream>>>(Oh, WOh, bo, out);
}

// Round 10
// 263.564 us; speedup vs baseline: 1.0459x; 1.0459x over previous
//
#include <hip/hip_runtime.h>
#include <hip/hip_bf16.h>

typedef unsigned short u16;
typedef unsigned int u32;
typedef __attribute__((ext_vector_type(8))) short s8v;    // 8 bf16 (4 VGPRs) — MFMA A/B frag
typedef __attribute__((ext_vector_type(4))) float f4v;    // MFMA C/D frag
typedef __attribute__((ext_vector_type(4))) unsigned short u16x4;
typedef __attribute__((ext_vector_type(4))) unsigned int u32x4;

#define MFMA16(a,b,c) __builtin_amdgcn_mfma_f32_16x16x32_bf16((a),(b),(c),0,0,0)

#define TOKENS 8192        // 4 * 2048
#define SEQ    2048
#define NH     16
#define DH     64
#define DIMK   1024
// fold 1/sqrt(64) * log2(e) into Q so P = exp2(S) directly
#define QPRE   0.18033688f

#if defined(__has_builtin)
#if __has_builtin(__builtin_amdgcn_exp2f)
#define EXP2(x) __builtin_amdgcn_exp2f(x)
#else
#define EXP2(x) __expf((x) * 0.69314718f)
#endif
#else
#define EXP2(x) __expf((x) * 0.69314718f)
#endif

// ---- bf16 helpers (round-to-nearest-even) ----
__device__ __forceinline__ u16 f2bf(float x){
  union { float f; u32 u; } v; v.f = x;
  u32 r = v.u + 0x7FFFu + ((v.u >> 16) & 1u);
  return (u16)(r >> 16);
}

// async global->LDS, 16B per lane; LDS dest = wave-uniform base + lane*16
__device__ __forceinline__ void gld16(const u16* g, u16* s){
  __builtin_amdgcn_global_load_lds(
      (const __attribute__((address_space(1))) unsigned int*)(const void*)g,
      (__attribute__((address_space(3))) unsigned int*)(void*)s,
      16, 0, 0);
}

// ---- cast fp32 -> bf16 (x) ----
__global__ __launch_bounds__(256) void k_cast(const float* __restrict__ src,
                                              u16* __restrict__ dst){
  int i = (blockIdx.x * 256 + threadIdx.x) * 4;
  float4 v = *(const float4*)(src + i);
  u16x4 vh;
  float a[4] = {v.x, v.y, v.z, v.w};
#pragma unroll
  for (int j = 0; j < 4; j++) vh[j] = f2bf(a[j]);
  *(u16x4*)(dst + i) = vh;
}

// ---- transpose weights to n-major bf16: out[n][k] = src[k][n] ----
__global__ __launch_bounds__(256) void k_transpose(const float* __restrict__ s0, int c0,
                                                   const float* __restrict__ s1, int c1,
                                                   int K, u16* __restrict__ dh){
  __shared__ float tile[64][65];
  int nb = blockIdx.x * 64, kb = blockIdx.y * 64;
  int tr = threadIdx.x >> 6, tc = threadIdx.x & 63;
#pragma unroll
  for (int i = 0; i < 16; i++){
    int k = kb + tr + i * 4, n = nb + tc;
    float v = (n < c0) ? s0[(size_t)k * c0 + n] : s1[(size_t)k * c1 + (n - c0)];
    tile[tr + i * 4][tc] = v;
  }
  __syncthreads();
#pragma unroll
  for (int i = 0; i < 16; i++){
    int nl = tr + i * 4, kl = tc;
    dh[(size_t)(nb + nl) * K + (kb + kl)] = f2bf(tile[kl][nl]);
  }
}

// ===========================================================================
// QKV GEMM — REVERTED to the round-8 measured-best config (81 µs): 256x256
// tile, BK=64, 512 threads, 8-phase dbuf schedule, 128 KiB LDS, LPT V-first
// order. NOTE (R9 lesson): occupancy is capped at 1 block/CU by REGISTERS
// (124 VGPR + 128 AGPR acc ≈ 252/wave -> 2 waves/SIMD), not LDS — so the
// in-block 8-phase prefetch is the only latency-hiding available; removing
// it (R9 single-buffer) cost +10 µs.
// ===========================================================================
#define GQ_STAGE_A(buf,h,t) do{ \
  gld16(As + (size_t)(h)*131072 + (size_t)(t)*64,      &lds[(buf)*32768 + (h)*8192 + w*512]); \
  gld16(As + (size_t)(h)*131072 + (size_t)(t)*64 + 32, &lds[(buf)*32768 + (h)*8192 + 4096 + w*512]); }while(0)
#define GQ_STAGE_B(buf,h,t) do{ \
  gld16(Bs + (size_t)(h)*131072 + (size_t)(t)*64,      &lds[(buf)*32768 + 16384 + (h)*8192 + w*512]); \
  gld16(Bs + (size_t)(h)*131072 + (size_t)(t)*64 + 32, &lds[(buf)*32768 + 16384 + (h)*8192 + 4096 + w*512]); }while(0)
#define GQ_RDA(dst,buf,mh) do{ _Pragma("unroll") for (int i_ = 0; i_ < 4; i_++){ \
  dst[i_][0] = *(const s8v*)&lds[(buf)*32768 + aRB + ((mh)*4+i_)*512]; \
  dst[i_][1] = *(const s8v*)&lds[(buf)*32768 + aRB + 4096 + ((mh)*4+i_)*512]; } }while(0)
#define GQ_RDB(dst,buf,nh) do{ _Pragma("unroll") for (int j_ = 0; j_ < 2; j_++){ \
  dst[j_][0] = *(const s8v*)&lds[(buf)*32768 + bRB + ((nh)*2+j_)*512]; \
  dst[j_][1] = *(const s8v*)&lds[(buf)*32768 + bRB + 4096 + ((nh)*2+j_)*512]; } }while(0)
#define GQ_MMA(aS,bS,mh,nh) do{ __builtin_amdgcn_s_setprio(1); \
  _Pragma("unroll") for (int i_ = 0; i_ < 4; i_++) \
  _Pragma("unroll") for (int j_ = 0; j_ < 2; j_++){ \
    acc[(mh)*4+i_][(nh)*2+j_] = MFMA16(aS[i_][0], bS[j_][0], acc[(mh)*4+i_][(nh)*2+j_]); \
    acc[(mh)*4+i_][(nh)*2+j_] = MFMA16(aS[i_][1], bS[j_][1], acc[(mh)*4+i_][(nh)*2+j_]); } \
  __builtin_amdgcn_s_setprio(0); }while(0)
#define GQ_BAR() do{ asm volatile("" ::: "memory"); __builtin_amdgcn_s_barrier(); asm volatile("" ::: "memory"); }while(0)
#define GQ_VMW2() asm volatile("s_waitcnt vmcnt(2)" ::: "memory")

__global__ __launch_bounds__(512, 2) void k_gemm_qkv(
    const u16* __restrict__ A, const u16* __restrict__ B,
    u16* __restrict__ Qh, u16* __restrict__ Kh, u16* __restrict__ Vth)
{
  __shared__ u16 lds[65536];   // 128 KiB
  const int tid = threadIdx.x;
  const int w = tid >> 6, lane = tid & 63;
  const int lm = lane & 15, quad = lane >> 4;
  const int wm = w >> 2, wn = w & 3;      // 2 x 4 wave grid; per-wave C: 128x64

  // m-partition XCD swizzle + LPT nt order (V-tiles first)
  const int bid = blockIdx.x;
  const int xcd = bid & 7, slot = bid >> 3;        // slot 0..47
  const int ntr = slot >> 2;                       // 0..11 (dispatch order)
  const int mloc = slot & 3;                       // 0..3
  const int nt = (ntr < 4) ? ntr + 8 : ntr - 4;
  const int m0 = (xcd * 4 + mloc) * 256, n0 = nt * 256;

  // stage-side per-lane source offsets (inverse swizzle applied to GLOBAL col)
  const int srow = lane >> 2;
  const int scol = ((lane & 3) ^ (((lane >> 5) & 1) << 1)) * 8;
  const u16* As = A + (size_t)(m0 + w * 16 + srow) * DIMK + scol;
  const u16* Bs = B + (size_t)(n0 + w * 16 + srow) * DIMK + scol;

  // read-side swizzled LDS bases (u16 units); col ^= 16 when lm >= 8
  const int swz = (lm & 8) << 1;
  const int aRB = wm * 8192 + lm * 32 + ((quad * 8) ^ swz);
  const int bRB = 16384 + (wn >> 1) * 8192 + (wn & 1) * 2048 + lm * 32 + ((quad * 8) ^ swz);

  f4v acc[8][4];
#pragma unroll
  for (int i = 0; i < 8; i++)
#pragma unroll
    for (int j = 0; j < 4; j++) acc[i][j] = (f4v){0.f, 0.f, 0.f, 0.f};

  // frag sets, read one phase ahead. a-sets ping-pong per K-tile parity;
  // bA always holds b(n0), bB always b(n1).
  s8v aA[4][2], aB[4][2], bA[2][2], bB[2][2];

  // prologue: stage kt0 {A0,A1,B0,B1} + kt1 A0; land kt0; read kt0 (m0,n0) frags
  GQ_STAGE_A(0,0,0); GQ_STAGE_A(0,1,0); GQ_STAGE_B(0,0,0); GQ_STAGE_B(0,1,0);
  GQ_STAGE_A(1,0,1);
  GQ_VMW2(); GQ_BAR();
  GQ_RDA(aA,0,0); GQ_RDB(bA,0,0);

  for (int it = 0; it < 8; it++){
    const int t1 = 2 * it + 1;
    const int t2 = (it < 7) ? 2 * it + 2 : 15;   // tail: re-stage kt15 (dead)
    const int t3 = (it < 7) ? 2 * it + 3 : 15;
    // ---- even kt = 2it (compute buf0; prefetch kt+1 -> buf1) ----
    GQ_STAGE_A(1,1,t1); GQ_BAR(); GQ_RDA(aB,0,1);                 GQ_MMA(aA,bA,0,0);
    GQ_STAGE_B(1,0,t1); GQ_BAR(); GQ_RDB(bB,0,1);                 GQ_MMA(aB,bA,1,0);
    GQ_STAGE_B(1,1,t1); GQ_BAR();                                 GQ_MMA(aB,bB,1,1);
    GQ_STAGE_A(0,0,t2); GQ_VMW2(); GQ_BAR();
                                  GQ_RDA(aB,1,0); GQ_RDB(bA,1,0); GQ_MMA(aA,bB,0,1);
    // ---- odd kt = 2it+1 (compute buf1; prefetch kt+1 -> buf0) ----
    GQ_STAGE_A(0,1,t2); GQ_BAR(); GQ_RDA(aA,1,1);                 GQ_MMA(aB,bA,0,0);
    GQ_STAGE_B(0,0,t2); GQ_BAR(); GQ_RDB(bB,1,1);                 GQ_MMA(aA,bA,1,0);
    GQ_STAGE_B(0,1,t2); GQ_BAR();                                 GQ_MMA(aA,bB,1,1);
    GQ_STAGE_A(1,0,t3); GQ_VMW2(); GQ_BAR();
                                  GQ_RDA(aA,0,0); GQ_RDB(bA,0,0); GQ_MMA(aB,bB,0,1);
  }

  // epilogue: C/D layout col = lane&15, row = quad*4+reg  [m89-verified]
  if (nt < 8){
    // Q / K tiles: direct stores (16 consecutive u16 per quad-row = 32B segs)
#pragma unroll
    for (int ig = 0; ig < 8; ig++)
#pragma unroll
      for (int jg = 0; jg < 4; jg++){
        const int gn = n0 + wn * 64 + jg * 16 + lm;
#pragma unroll
        for (int r = 0; r < 4; r++){
          const int gm = m0 + wm * 128 + ig * 16 + quad * 4 + r;
          float v = acc[ig][jg][r];
          if (gn < 1024){                       // Q, token-major, pre-scaled
            Qh[(size_t)gm * DIMK + gn] = f2bf(v * QPRE);
          } else {                              // K, token-major
            Kh[(size_t)gm * DIMK + (gn - 1024)] = f2bf(v);
          }
        }
      }
  } else {
    // V tile: LDS transpose bounce with tau permutation (within each
    // 64-token group). acc token t64 = (ig&3)*16 + quad*4 + r maps to
    // storage pos64 = ip^-1(t64) = ((ig>>1)&1)*32 + quad*8 + (ig&1)*4 + r.
    // u32 words pair consecutive r -> per (igp, jg) one u32x4 at
    //   colb = (wm*2 + (igp>>1))*32 + (igp&1)*16 + quad*4.
    __syncthreads();   // drain K-loop LDS reads + outstanding (dead) gld16s
    u32* bnc = (u32*)lds;
#pragma unroll
    for (int igp = 0; igp < 4; igp++)
#pragma unroll
      for (int jg = 0; jg < 4; jg++){
        const int ddl = wn * 64 + jg * 16 + lm;          // 0..255 (d dim)
        const int colb = (wm * 2 + (igp >> 1)) * 32 + (igp & 1) * 16 + quad * 4;
        u32x4 p;
        p[0] = ((u32)f2bf(acc[2 * igp][jg][1])     << 16) | (u32)f2bf(acc[2 * igp][jg][0]);
        p[1] = ((u32)f2bf(acc[2 * igp][jg][3])     << 16) | (u32)f2bf(acc[2 * igp][jg][2]);
        p[2] = ((u32)f2bf(acc[2 * igp + 1][jg][1]) << 16) | (u32)f2bf(acc[2 * igp + 1][jg][0]);
        p[3] = ((u32)f2bf(acc[2 * igp + 1][jg][3]) << 16) | (u32)f2bf(acc[2 * igp + 1][jg][2]);
        const int col = colb ^ ((lm & 7) << 2);          // involution, 16B-granular
        *(u32x4*)&bnc[ddl * 128 + col] = p;
      }
    __syncthreads();
    // coalesced store: 2 threads per dd-row, 256B each (4x dwordx4), rows
    // are contiguous 512B runs in Vth (tau stays inside 64-token groups).
    const int row = tid >> 1, half = tid & 1;
    const int df = n0 - 2048 + row;
    const int hh = df >> 6, dd = df & 63;
    const int bbat = m0 >> 11, ii0 = m0 & 2047;
    u32* Vg = (u32*)(Vth + ((size_t)(bbat * NH + hh) * DH + dd) * SEQ + ii0);
#pragma unroll
    for (int c = 0; c < 16; c++){
      const int cc = half * 16 + c;
      const int cb = (cc * 4) ^ ((row & 7) << 2);
      u32x4 q = *(const u32x4*)&bnc[row * 128 + cb];
      *(u32x4*)&Vg[cc * 4] = q;
    }
  }
}

// ---- out-proj GEMM: BM=64 x BN=128, BK=64, m-partition XCD swizzle ----
// R7 structure (single-buffer, 24 KB LDS, 4 blocks/CU) + NEW: ONLY the
// stage/read swizzle pair (isolated from R8's confounded dbuf+swizzle —
// the dbuf's LDS growth cost a block/CU). Un-swizzled fragment reads were
// an 8-way bank conflict (rows stride 64 B).
__global__ __launch_bounds__(256) void k_gemm_op(
    const u16* __restrict__ A, const u16* __restrict__ B,
    const float* __restrict__ bias, float* __restrict__ Cf)
{
  __shared__ u16 sA[2][64*32], sB[2][128*32];   // 8 + 16 = 24 KB
  const int tid = threadIdx.x, wave = tid >> 6, lane = tid & 63;
  const int lm = lane & 15, quad = lane >> 4;

  const int bid = blockIdx.x;                    // 1024 = 8 xcd x 128 slots
  const int xcd = bid & 7, slot = bid >> 3;      // slot 0..127
  const int nt = slot >> 4, mloc = slot & 15;    // nt 0..7, mloc 0..15
  const int m0 = (xcd * 16 + mloc) * 64, n0 = nt * 128;

  const int rsub = lane >> 2;
  // stage-side inverse-swizzled global col16; read-side XOR term (u16)
  const int scof = ((lane & 3) ^ (((lane >> 5) & 1) << 1)) * 8;
  const int rsw = (lm & 8) << 1;

  f4v acc[2][4];
#pragma unroll
  for (int i = 0; i < 2; i++)
#pragma unroll
    for (int j = 0; j < 4; j++) acc[i][j] = (f4v){0.f, 0.f, 0.f, 0.f};

  const int wm = (wave >> 1) * 32, wn = (wave & 1) * 64;

  for (int kc = 0; kc < 16; kc++){
    int k = kc * 64;
#pragma unroll
    for (int cc = 0; cc < 2; cc++){
      gld16(A + (size_t)(m0 + wave * 16 + rsub) * DIMK + k + cc * 32 + scof, &sA[cc][wave * 512]);
#pragma unroll
      for (int h = 0; h < 2; h++)
        gld16(B + (size_t)(n0 + h * 64 + wave * 16 + rsub) * DIMK + k + cc * 32 + scof,
              &sB[cc][h * 2048 + wave * 512]);
    }
    __syncthreads();

#pragma unroll
    for (int cc = 0; cc < 2; cc++){
      s8v ah[2], bh[4];
#pragma unroll
      for (int i = 0; i < 2; i++)
        ah[i] = *(const s8v*)&sA[cc][(wm + i * 16 + lm) * 32 + ((quad * 8) ^ rsw)];
#pragma unroll
      for (int j = 0; j < 4; j++)
        bh[j] = *(const s8v*)&sB[cc][(wn + j * 16 + lm) * 32 + ((quad * 8) ^ rsw)];
#pragma unroll
      for (int i = 0; i < 2; i++)
#pragma unroll
        for (int j = 0; j < 4; j++)
          acc[i][j] = MFMA16(ah[i], bh[j], acc[i][j]);
    }
    __syncthreads();
  }

#pragma unroll
  for (int i = 0; i < 2; i++)
#pragma unroll
    for (int j = 0; j < 4; j++){
      int gn = n0 + wn + j * 16 + lm;
      float bv = bias[gn];
#pragma unroll
      for (int r = 0; r < 4; r++){
        int gm = m0 + wm + i * 16 + quad * 4 + r;
        Cf[(size_t)gm * DIMK + gn] = acc[i][j][r] + bv;
      }
    }
}

// ---- flash attention, max-free softmax, XCD (b,h)-grouping ----
// Swapped QK^T (mfma(K,Q)) puts each lane's P slice lane-local (col=lm=q)
// -> P packs straight into PV A-frags in registers. sP deleted. A-frag
// k-slot j of chunk c holds kv=(2c+(j>>2))*16+quad*4+(j&3), matched by the
// tau ordering of Vth columns (qkv epilogue). dbuf + vmcnt(4) + raw
// barriers. Unchanged (passed rounds 7-9).
__global__ __launch_bounds__(256, 2) void k_attn(
    const u16* __restrict__ Qh, const u16* __restrict__ Kh, const u16* __restrict__ Vth,
    u16* __restrict__ Oh)
{
  __shared__ u16 sK[2*4096];       // [buf][c][j(64)][32]   16 KB
  __shared__ u16 sV[2*4096];       // [buf][c][d(64)][32 j-tau] 16 KB

  // XCD-aware (b,h,qt) assignment: 512 blocks = 8 xcd x 8 bh x 8 qt
  const int bid = blockIdx.x;
  const int xcd = bid & 7, slot = bid >> 3;      // slot 0..63
  const int g = xcd * 8 + (slot >> 3);           // (b,h) group 0..63
  const int qt = slot & 7;
  const int b = g >> 4, h = g & 15;

  const int tid = threadIdx.x, wave = tid >> 6, lane = tid & 63;
  const int lm = lane & 15, quad = lane >> 4;
  const int tok0 = b * SEQ + qt * 256;
  const int rsub = lane >> 2;
  // stage-side inverse-swizzled global col16; read-side XOR term (u16)
  const int scof = ((lane & 3) ^ (((lane >> 5) & 1) << 1)) * 8;
  const int rsw = (lm & 8) << 1;

  // Q fragments straight to registers (now the B-operand: n=q=lm)
  s8v qf[2][4];   // [c][ifr]
#pragma unroll
  for (int c = 0; c < 2; c++)
#pragma unroll
    for (int ifr = 0; ifr < 4; ifr++){
      size_t ga = (size_t)(tok0 + wave * 64 + ifr * 16 + lm) * DIMK + h * DH + c * 32 + quad * 8;
      qf[c][ifr] = *(const s8v*)(Qh + ga);
    }

  const f4v fz = (f4v){0.f, 0.f, 0.f, 0.f};   // persistent zero C-operand

  s8v ones;                                   // bf16 1.0 B-fragment for l-sum
#pragma unroll
  for (int j = 0; j < 8; j++) ones[j] = (short)0x3F80;

  f4v oacc[4][4];
  f4v lacc[4];
#pragma unroll
  for (int ifr = 0; ifr < 4; ifr++){
    lacc[ifr] = (f4v){0.f, 0.f, 0.f, 0.f};
#pragma unroll
    for (int fd = 0; fd < 4; fd++) oacc[ifr][fd] = (f4v){0.f, 0.f, 0.f, 0.f};
  }

#define AT_STAGE(p, t) do{ const int jb_ = (t) * 64; \
  _Pragma("unroll") for (int c_ = 0; c_ < 2; c_++){ \
    gld16(Kh + (size_t)(b * SEQ + jb_ + wave * 16 + rsub) * DIMK + h * DH + c_ * 32 + scof, \
          &sK[(p) * 4096 + c_ * 2048 + wave * 512]); \
    gld16(Vth + (size_t)((b * NH + h) * DH + wave * 16 + rsub) * SEQ + jb_ + c_ * 32 + scof, \
          &sV[(p) * 4096 + c_ * 2048 + wave * 512]); } }while(0)
#define AT_BAR() do{ asm volatile("" ::: "memory"); __builtin_amdgcn_s_barrier(); asm volatile("" ::: "memory"); }while(0)

  // prologue: stage kt0 -> buf0
  AT_STAGE(0, 0);

  for (int kt = 0; kt < 32; kt++){
    const int p = kt & 1;
    // prefetch kt+1 into the other buffer (dead re-stage of kt=31 on last)
    AT_STAGE(p ^ 1, (kt < 31) ? (kt + 1) : 31);
    // wait only for kt's 4 loads (kt+1's 4 stay in flight across the barrier)
    asm volatile("s_waitcnt vmcnt(4)" ::: "memory");
    AT_BAR();
    const int pb = p * 4096;

    // K fragments (A-operand now; same reads), reused by all 4 ifr
    s8v kh[2][4];
#pragma unroll
    for (int fn = 0; fn < 4; fn++){
      kh[0][fn] = *(const s8v*)&sK[pb + (fn * 16 + lm) * 32 + ((quad * 8) ^ rsw)];
      kh[1][fn] = *(const s8v*)&sK[pb + 2048 + (fn * 16 + lm) * 32 + ((quad * 8) ^ rsw)];
    }

    // per ifr: swapped S^T = K Q^T (lane: q = ifr*16+lm, kv = fn*16+quad*4+r);
    // P = exp2 in-register; pack to PV A-frags pa[ifr][c]:
    //   element j of chunk c = st[2c+(j>>2)][j&3]  (kv matches tau-ordered V)
    s8v pa[4][2];
#pragma unroll
    for (int ifr = 0; ifr < 4; ifr++){
      f4v st[4];
      __builtin_amdgcn_s_setprio(1);
#pragma unroll
      for (int fn = 0; fn < 4; fn++){
        st[fn] = MFMA16(kh[0][fn], qf[0][ifr], fz);
        st[fn] = MFMA16(kh[1][fn], qf[1][ifr], st[fn]);
      }
      __builtin_amdgcn_s_setprio(0);
#pragma unroll
      for (int fn = 0; fn < 4; fn++)
#pragma unroll
        for (int r = 0; r < 4; r++)
          st[fn][r] = EXP2(st[fn][r]);
#pragma unroll
      for (int c = 0; c < 2; c++){
        union { u32x4 w; s8v v; } u;
#pragma unroll
        for (int w2 = 0; w2 < 4; w2++){
          const int fn = c * 2 + (w2 >> 1);
          const int rr = (w2 & 1) * 2;
          union { float f; u32 u; } a0, a1;
          a0.f = st[fn][rr]; a1.f = st[fn][rr + 1];
          u.w[w2] = __builtin_amdgcn_perm(a1.u, a0.u, 0x07060302);
        }
        pa[ifr][c] = u.v;
      }
    }

    // V fragments (tau-ordered columns; read once, reused by all 4 ifr)
    s8v vreg[2][4];
#pragma unroll
    for (int c = 0; c < 2; c++)
#pragma unroll
      for (int fd = 0; fd < 4; fd++)
        vreg[c][fd] = *(const s8v*)&sV[pb + c * 2048 + (fd * 16 + lm) * 32 + ((quad * 8) ^ rsw)];

    // O += P V ; l += P·1  (all in registers — no LDS round-trip for P)
    __builtin_amdgcn_s_setprio(1);
#pragma unroll
    for (int c = 0; c < 2; c++)
#pragma unroll
      for (int ifr = 0; ifr < 4; ifr++){
#pragma unroll
        for (int fd = 0; fd < 4; fd++)
          oacc[ifr][fd] = MFMA16(pa[ifr][c], vreg[c][fd], oacc[ifr][fd]);
        lacc[ifr] = MFMA16(pa[ifr][c], ones, lacc[ifr]);
      }
    __builtin_amdgcn_s_setprio(0);
    // all waves done reading buf p before iter kt+1 overwrites it
    AT_BAR();
  }

  // normalize + store (lacc[ifr][r] = rowsum for q-row quad*4+r)
#pragma unroll
  for (int ifr = 0; ifr < 4; ifr++){
    float inv[4];
#pragma unroll
    for (int r = 0; r < 4; r++) inv[r] = 1.f / lacc[ifr][r];
#pragma unroll
    for (int fd = 0; fd < 4; fd++){
      int dcol = h * DH + fd * 16 + lm;
#pragma unroll
      for (int r = 0; r < 4; r++){
        int tok = tok0 + wave * 64 + ifr * 16 + quad * 4 + r;
        Oh[(size_t)tok * DIMK + dcol] = f2bf(oacc[ifr][fd][r] * inv[r]);
      }
    }
  }
}

extern "C" void kernel_launch(void* const* d_in, const int* in_sizes, int n_in,
                              void* d_out, int out_size, void* d_ws, size_t ws_size,
                              hipStream_t stream) {
  const float* x   = (const float*)d_in[0];
  const float* Wq  = (const float*)d_in[1];
  const float* Wkv = (const float*)d_in[2];
  const float* Wo  = (const float*)d_in[3];
  const float* bo  = (const float*)d_in[4];
  float* out = (float*)d_out;

  char* ws = (char*)d_ws;
  size_t off = 0;
  auto alloc = [&](size_t bytes) -> u16* {
    u16* p = (u16*)(ws + off);
    off += (bytes + 255) & ~(size_t)255;
    return p;
  };
  const size_t TK2 = (size_t)TOKENS * DIMK * 2;   // 16.78 MB per bf16 plane
  u16* xh  = alloc(TK2);
  u16* Wh  = alloc((size_t)3072 * DIMK * 2);      // [Wq|Wkv]^T  [3072][1024]
  u16* WOh = alloc((size_t)1024 * DIMK * 2);      // Wo^T        [1024][1024]
  u16* Qh  = alloc(TK2);
  u16* Kh  = alloc(TK2);
  u16* Vth = alloc(TK2);
  u16* Oh  = alloc(TK2);

  // 1) cast x to bf16
  k_cast<<<dim3((TOKENS * DIMK) / 1024), 256, 0, stream>>>(x, xh);
  // 2) transpose weights to n-major
  k_transpose<<<dim3(48, 16), 256, 0, stream>>>(Wq, 1024, Wkv, 2048, DIMK, Wh);
  k_transpose<<<dim3(16, 16), 256, 0, stream>>>(Wo, 1024, Wo, 1024, DIMK, WOh);
  // 3) QKV projection: R8 config (8-phase, 128 KiB dbuf, LPT V-first)
  k_gemm_qkv<<<dim3(384), 512, 0, stream>>>(xh, Wh, Qh, Kh, Vth);
  // 4) flash attention: in-register P, 64 q-rows/wave, 2 blocks/CU
  k_attn<<<dim3(512), 256, 0, stream>>>(Qh, Kh, Vth, Oh);
  // 5) output projection + bias: R7 form + swizzle pair (24 KB, 4 blocks/CU)
  k_gemm_op<<<dim3(1024), 256, 0, stream>>>(Oh, WOh, bo, out);
}